// Round 10
// baseline (760.711 us; speedup 1.0000x reference)
//
#include <hip/hip_runtime.h>
#include <cmath>

#define NEG_SLOPE 0.2f

typedef __attribute__((ext_vector_type(4))) float f32x4;
typedef __attribute__((ext_vector_type(8))) short s16x8;

__device__ inline unsigned short bf16rn(float x) {
    unsigned int u = __float_as_uint(x);
    u += 0x7fffu + ((u >> 16) & 1u);
    return (unsigned short)(u >> 16);
}
__device__ inline float bf16tof(unsigned short h) {
    return __uint_as_float(((unsigned int)h) << 16);
}

__device__ inline void fma4(float acc[4], const float4 a, const float4 w0,
                            const float4 w1, const float4 w2, const float4 w3) {
    acc[0] += a.x*w0.x + a.y*w1.x + a.z*w2.x + a.w*w3.x;
    acc[1] += a.x*w0.y + a.y*w1.y + a.z*w2.y + a.w*w3.y;
    acc[2] += a.x*w0.z + a.y*w1.z + a.z*w2.z + a.w*w3.z;
    acc[3] += a.x*w0.w + a.y*w1.w + a.z*w2.w + a.w*w3.w;
}

// ---------------------------------------------------------------- weight split (batched, 7 weights)
// Each W is [256][128] fp32 -> fragment-major bf16 hi/lo planes (32768 shorts each).
// slot tid = (nt*8 + kt)*64 + lane ; element j: W[kt*32 + (lane>>4)*8 + j][nt*16 + (lane&15)]
__global__ __launch_bounds__(256) void split_w7(const float* __restrict__ w0,
                                                const float* __restrict__ w1,
                                                const float* __restrict__ w2,
                                                const float* __restrict__ w3,
                                                const float* __restrict__ w4,
                                                const float* __restrict__ w5,
                                                const float* __restrict__ w6,
                                                unsigned short* __restrict__ whi,
                                                unsigned short* __restrict__ wlo) {
    const int widx = blockIdx.y;
    const float* W = widx == 0 ? w0 : widx == 1 ? w1 : widx == 2 ? w2 :
                     widx == 3 ? w3 : widx == 4 ? w4 : widx == 5 ? w5 : w6;
    int tid = blockIdx.x * 256 + threadIdx.x;      // 0..4095
    int nt = tid >> 9, kt = (tid >> 6) & 7, l = tid & 63;
    int col   = nt * 16 + (l & 15);
    int kbase = kt * 32 + (l >> 4) * 8;
    size_t base = (size_t)widx * 32768 + (size_t)tid * 8;
#pragma unroll
    for (int j = 0; j < 8; ++j) {
        float x = W[(kbase + j) * 128 + col];
        unsigned short hi = bf16rn(x);
        unsigned short lo = bf16rn(x - bf16tof(hi));
        whi[base + j] = hi;
        wlo[base + j] = lo;
    }
}

// bconst[j] = [b_ll | 0.5(b_mm+b_lm)] @ gate_W + gate_b
__global__ __launch_bounds__(128) void bconst_k(const float* __restrict__ W,
                                                const float* __restrict__ gate_b,
                                                const float* __restrict__ b_ll,
                                                const float* __restrict__ b_mm,
                                                const float* __restrict__ b_lm,
                                                float* __restrict__ bconst) {
    int j = threadIdx.x;
    float s = gate_b[j];
    for (int k = 0; k < 128; ++k) s += b_ll[k] * W[k * 128 + j];
    for (int k = 0; k < 128; ++k)
        s += 0.5f * (b_mm[k] + b_lm[k]) * W[(128 + k) * 128 + j];
    bconst[j] = s;
}

// ---------------------------------------------------------------- CSR build (batched)
__global__ __launch_bounds__(256) void zero_int(int* p, int n) {
    int i = blockIdx.x * 256 + threadIdx.x;
    if (i < n) p[i] = 0;
}

__global__ __launch_bounds__(256) void hist3(const int* __restrict__ e0,
                                             const int* __restrict__ e1,
                                             const int* __restrict__ e2,
                                             int* __restrict__ counts3, int E, int N) {
    int c = blockIdx.y;
    const int* et = (c == 0 ? e0 : c == 1 ? e1 : e2) + E;
    int e = blockIdx.x * 256 + threadIdx.x;
    if (e < E) atomicAdd(&counts3[c * N + et[e]], 1);
}

__global__ __launch_bounds__(1024) void scan3(const int* __restrict__ counts3,
                                              int* __restrict__ base3,
                                              int* __restrict__ cursor3, int n) {
    __shared__ int tot[1024];
    const int c = blockIdx.x;
    const int* counts = counts3 + c * n;
    int* base   = base3 + c * n;
    int* cursor = cursor3 + c * n;
    const int t = threadIdx.x;
    const int chunk = (n + 1023) >> 10;
    const int i0 = t * chunk;
    int s = 0;
    for (int i = 0; i < chunk; ++i) {
        int idx = i0 + i;
        if (idx < n) s += counts[idx];
    }
    tot[t] = s;
    __syncthreads();
    for (int d = 1; d < 1024; d <<= 1) {
        int v = (t >= d) ? tot[t - d] : 0;
        __syncthreads();
        tot[t] += v;
        __syncthreads();
    }
    int run = (t == 0) ? 0 : tot[t - 1];
    for (int i = 0; i < chunk; ++i) {
        int idx = i0 + i;
        if (idx < n) {
            base[idx]   = run;
            cursor[idx] = run;
            run += counts[idx];
        }
    }
}

__global__ __launch_bounds__(256) void scatter_edges(const int* __restrict__ esrc,
                                                     const int* __restrict__ etgt,
                                                     int* __restrict__ cursor,
                                                     int* __restrict__ perm, int E) {
    int e = blockIdx.x * 256 + threadIdx.x;
    if (e >= E) return;
    int pos = atomicAdd(&cursor[etgt[e]], 1);
    perm[pos] = esrc[e];
}

// ---------------------------------------------------------------- MFMA projection GEMM
template <int NW>
__global__ __launch_bounds__(256) void gemm_mfma(const float* __restrict__ A,
                                                 const unsigned short* __restrict__ w1hi,
                                                 const unsigned short* __restrict__ w1lo,
                                                 const unsigned short* __restrict__ w2hi,
                                                 const unsigned short* __restrict__ w2lo,
                                                 float* __restrict__ C1,
                                                 float* __restrict__ C2, int M) {
    const int t = threadIdx.x;
    const int w = t >> 6, l = t & 63;
    const int lg = l >> 4, lr = l & 15;
    const int row  = blockIdx.x * 64 + w * 16 + lr;
    const int arow = row < M ? row : M - 1;

    s16x8 ahi[8], alo[8];
#pragma unroll
    for (int kt = 0; kt < 8; ++kt) {
        const float* ap = &A[(size_t)arow * 256 + kt * 32 + lg * 8];
        float4 f0 = *(const float4*)ap;
        float4 f1 = *(const float4*)(ap + 4);
        float xs[8] = {f0.x, f0.y, f0.z, f0.w, f1.x, f1.y, f1.z, f1.w};
        s16x8 h, lo;
#pragma unroll
        for (int j = 0; j < 8; ++j) {
            unsigned short hh = bf16rn(xs[j]);
            h[j]  = (short)hh;
            lo[j] = (short)bf16rn(xs[j] - bf16tof(hh));
        }
        ahi[kt] = h;
        alo[kt] = lo;
    }

    const int orow0 = blockIdx.x * 64 + w * 16 + lg * 4;
#pragma unroll
    for (int ph = 0; ph < NW; ++ph) {
        const unsigned short* whi = ph ? w2hi : w1hi;
        const unsigned short* wlo = ph ? w2lo : w1lo;
        float* __restrict__ C     = ph ? C2 : C1;
        f32x4 acc[8];
#pragma unroll
        for (int nt = 0; nt < 8; ++nt) acc[nt] = (f32x4){0.f, 0.f, 0.f, 0.f};
#pragma unroll
        for (int kt = 0; kt < 8; ++kt) {
#pragma unroll
            for (int nt = 0; nt < 8; ++nt) {
                const int boff = ((nt * 8 + kt) * 64 + l) * 8;
                s16x8 bhi = *(const s16x8*)&whi[boff];
                s16x8 blo = *(const s16x8*)&wlo[boff];
                acc[nt] = __builtin_amdgcn_mfma_f32_16x16x32_bf16(alo[kt], bhi, acc[nt], 0, 0, 0);
                acc[nt] = __builtin_amdgcn_mfma_f32_16x16x32_bf16(ahi[kt], blo, acc[nt], 0, 0, 0);
                acc[nt] = __builtin_amdgcn_mfma_f32_16x16x32_bf16(ahi[kt], bhi, acc[nt], 0, 0, 0);
            }
        }
#pragma unroll
        for (int nt = 0; nt < 8; ++nt) {
#pragma unroll
            for (int r = 0; r < 4; ++r) {
                int orow = orow0 + r;
                if (orow < M) C[(size_t)orow * 128 + nt * 16 + lr] = acc[nt][r];
            }
        }
    }
}

// two independent single-output GEMMs in one launch (blockIdx.y selects)
__global__ __launch_bounds__(256) void gemm_mfma_pair(const float* __restrict__ A0,
                                                      const float* __restrict__ A1,
                                                      const unsigned short* __restrict__ wahi,
                                                      const unsigned short* __restrict__ walo,
                                                      const unsigned short* __restrict__ wbhi,
                                                      const unsigned short* __restrict__ wblo,
                                                      float* __restrict__ C0,
                                                      float* __restrict__ C1, int M) {
    const int t = threadIdx.x;
    const int w = t >> 6, l = t & 63;
    const int lg = l >> 4, lr = l & 15;
    const int row  = blockIdx.x * 64 + w * 16 + lr;
    const int arow = row < M ? row : M - 1;
    const float* __restrict__ A = blockIdx.y ? A1 : A0;
    const unsigned short* __restrict__ whi = blockIdx.y ? wbhi : wahi;
    const unsigned short* __restrict__ wlo = blockIdx.y ? wblo : walo;
    float* __restrict__ C = blockIdx.y ? C1 : C0;

    s16x8 ahi[8], alo[8];
#pragma unroll
    for (int kt = 0; kt < 8; ++kt) {
        const float* ap = &A[(size_t)arow * 256 + kt * 32 + lg * 8];
        float4 f0 = *(const float4*)ap;
        float4 f1 = *(const float4*)(ap + 4);
        float xs[8] = {f0.x, f0.y, f0.z, f0.w, f1.x, f1.y, f1.z, f1.w};
        s16x8 h, lo;
#pragma unroll
        for (int j = 0; j < 8; ++j) {
            unsigned short hh = bf16rn(xs[j]);
            h[j]  = (short)hh;
            lo[j] = (short)bf16rn(xs[j] - bf16tof(hh));
        }
        ahi[kt] = h;
        alo[kt] = lo;
    }

    f32x4 acc[8];
#pragma unroll
    for (int nt = 0; nt < 8; ++nt) acc[nt] = (f32x4){0.f, 0.f, 0.f, 0.f};
#pragma unroll
    for (int kt = 0; kt < 8; ++kt) {
#pragma unroll
        for (int nt = 0; nt < 8; ++nt) {
            const int boff = ((nt * 8 + kt) * 64 + l) * 8;
            s16x8 bhi = *(const s16x8*)&whi[boff];
            s16x8 blo = *(const s16x8*)&wlo[boff];
            acc[nt] = __builtin_amdgcn_mfma_f32_16x16x32_bf16(alo[kt], bhi, acc[nt], 0, 0, 0);
            acc[nt] = __builtin_amdgcn_mfma_f32_16x16x32_bf16(ahi[kt], blo, acc[nt], 0, 0, 0);
            acc[nt] = __builtin_amdgcn_mfma_f32_16x16x32_bf16(ahi[kt], bhi, acc[nt], 0, 0, 0);
        }
    }
    const int orow0 = blockIdx.x * 64 + w * 16 + lg * 4;
#pragma unroll
    for (int nt = 0; nt < 8; ++nt) {
#pragma unroll
        for (int r = 0; r < 4; ++r) {
            int orow = orow0 + r;
            if (orow < M) C[(size_t)orow * 128 + nt * 16 + lr] = acc[nt][r];
        }
    }
}

// ---------------------------------------------------------------- fused per-node GATv2
// Half-wave (32 lanes) per node; lane q covers channels 4q..4q+3; head = q>>4.
// Online softmax; zero atomics. MODE 0: h=agg ; 1: h=0.5*agg ; 2: h+=0.5*agg
#define LEAKY(z) ((z) > 0.f ? (z) : NEG_SLOPE * (z))
#define HREDUCE(p) { p += __shfl_xor(p, 1); p += __shfl_xor(p, 2); \
                     p += __shfl_xor(p, 4); p += __shfl_xor(p, 8); }

__device__ inline float dot4l(const float4 x, const float4 xr, const float4 a) {
    return LEAKY(x.x + xr.x) * a.x + LEAKY(x.y + xr.y) * a.y +
           LEAKY(x.z + xr.z) * a.z + LEAKY(x.w + xr.w) * a.w;
}

template <int MODE>
__global__ __launch_bounds__(256) void node_gatv2(const float* __restrict__ xl,
                                                  const float* __restrict__ xr,
                                                  const float* __restrict__ att,
                                                  const int* __restrict__ base,
                                                  const int* __restrict__ counts,
                                                  const int* __restrict__ perm,
                                                  unsigned short* __restrict__ hhi,
                                                  unsigned short* __restrict__ hlo,
                                                  int N) {
    const int node = blockIdx.x * 8 + (threadIdx.x >> 5);
    if (node >= N) return;
    const int q = threadIdx.x & 31;

    const float4 xrv  = *(const float4*)&xr[(size_t)node * 128 + q * 4];
    const float4 attv = *(const float4*)&att[q * 4];
    const int b   = base[node];
    const int deg = counts[node];

    float  m   = -INFINITY;
    float  den = 0.0f;
    float4 acc = {0.0f, 0.0f, 0.0f, 0.0f};

    int k = 0;
    for (; k + 3 < deg; k += 4) {
        int s0 = perm[b + k + 0];
        int s1 = perm[b + k + 1];
        int s2 = perm[b + k + 2];
        int s3 = perm[b + k + 3];
        float4 x0 = *(const float4*)&xl[(size_t)s0 * 128 + q * 4];
        float4 x1 = *(const float4*)&xl[(size_t)s1 * 128 + q * 4];
        float4 x2 = *(const float4*)&xl[(size_t)s2 * 128 + q * 4];
        float4 x3 = *(const float4*)&xl[(size_t)s3 * 128 + q * 4];

        float p0 = dot4l(x0, xrv, attv);
        float p1 = dot4l(x1, xrv, attv);
        float p2 = dot4l(x2, xrv, attv);
        float p3 = dot4l(x3, xrv, attv);
        HREDUCE(p0) HREDUCE(p1) HREDUCE(p2) HREDUCE(p3)

        float mn = fmaxf(fmaxf(fmaxf(m, p0), fmaxf(p1, p2)), p3);
        float f  = expf(m  - mn);
        float e0 = expf(p0 - mn);
        float e1 = expf(p1 - mn);
        float e2 = expf(p2 - mn);
        float e3 = expf(p3 - mn);
        den   = den   * f + e0 + e1 + e2 + e3;
        acc.x = acc.x * f + e0 * x0.x + e1 * x1.x + e2 * x2.x + e3 * x3.x;
        acc.y = acc.y * f + e0 * x0.y + e1 * x1.y + e2 * x2.y + e3 * x3.y;
        acc.z = acc.z * f + e0 * x0.z + e1 * x1.z + e2 * x2.z + e3 * x3.z;
        acc.w = acc.w * f + e0 * x0.w + e1 * x1.w + e2 * x2.w + e3 * x3.w;
        m = mn;
    }
    for (; k < deg; ++k) {
        int src = perm[b + k];
        float4 x = *(const float4*)&xl[(size_t)src * 128 + q * 4];
        float p = dot4l(x, xrv, attv);
        HREDUCE(p)
        float mn = fmaxf(m, p);
        float f  = expf(m - mn);
        float ex = expf(p - mn);
        den   = den   * f + ex;
        acc.x = acc.x * f + ex * x.x;
        acc.y = acc.y * f + ex * x.y;
        acc.z = acc.z * f + ex * x.z;
        acc.w = acc.w * f + ex * x.w;
        m = mn;
    }

    const float scale = (MODE == 0) ? 1.0f : 0.5f;
    const float r = scale / fmaxf(den, 1e-16f);
    float o[4] = {acc.x * r, acc.y * r, acc.z * r, acc.w * r};

    const size_t idx = (size_t)node * 128 + q * 4;
    if (MODE == 2) {
        ushort4 ph = *(const ushort4*)&hhi[idx];
        ushort4 pl = *(const ushort4*)&hlo[idx];
        o[0] += bf16tof(ph.x) + bf16tof(pl.x);
        o[1] += bf16tof(ph.y) + bf16tof(pl.y);
        o[2] += bf16tof(ph.z) + bf16tof(pl.z);
        o[3] += bf16tof(ph.w) + bf16tof(pl.w);
    }
    ushort4 vh, vl;
    unsigned short h0 = bf16rn(o[0]); vh.x = h0; vl.x = bf16rn(o[0] - bf16tof(h0));
    unsigned short h1 = bf16rn(o[1]); vh.y = h1; vl.y = bf16rn(o[1] - bf16tof(h1));
    unsigned short h2 = bf16rn(o[2]); vh.z = h2; vl.z = bf16rn(o[2] - bf16tof(h2));
    unsigned short h3 = bf16rn(o[3]); vh.w = h3; vl.w = bf16rn(o[3] - bf16tof(h3));
    *(ushort4*)&hhi[idx] = vh;
    *(ushort4*)&hlo[idx] = vl;
}

// ---------------------------------------------------------------- pair MLP (MFMA gate, 2 row-tiles/wave)
// 128 pairs/block, 256 threads (4 waves x 32 pairs). LDS 67.6 KB -> 2 blocks/CU.
__global__ __launch_bounds__(256) void mlp_fused(
        const unsigned short* __restrict__ hlhi, const unsigned short* __restrict__ hllo,
        const unsigned short* __restrict__ hmhi, const unsigned short* __restrict__ hmlo,
        const int* __restrict__ pairs, int P,
        const unsigned short* __restrict__ whi, const unsigned short* __restrict__ wlo,
        const float* __restrict__ bconst,
        const float* __restrict__ b_ll, const float* __restrict__ b_mm,
        const float* __restrict__ b_lm,
        const float* __restrict__ c1_W, const float* __restrict__ c1_b,
        const float* __restrict__ c2_W, const float* __restrict__ c2_b,
        const float* __restrict__ c3_W, const float* __restrict__ c3_b,
        float* __restrict__ out) {
    __shared__ float fus[128][132];       // 67584 B; later overlaid by h1 (stride 68) and h2 (stride 33)
    float* ldsf = &fus[0][0];
    const int t  = threadIdx.x;
    const int pb = blockIdx.x * 128;

    // ---- gate GEMM via MFMA bf16 hi/lo split; 2 row-tiles per wave ----
    {
        const int w = t >> 6, l = t & 63;
        const int lg = l >> 4, lr = l & 15;
        int p0i = pb + w * 32 + lr;       // tile 0 rows
        int p1i = p0i + 16;               // tile 1 rows
        if (p0i >= P) p0i = P - 1;
        if (p1i >= P) p1i = P - 1;
        const int r1a = pairs[p0i * 2 + 0], r2a = pairs[p0i * 2 + 1];
        const int r1b = pairs[p1i * 2 + 0], r2b = pairs[p1i * 2 + 1];

        f32x4 acc0[8], acc1[8];
#pragma unroll
        for (int nt = 0; nt < 8; ++nt) {
            acc0[nt] = (f32x4){0.f, 0.f, 0.f, 0.f};
            acc1[nt] = (f32x4){0.f, 0.f, 0.f, 0.f};
        }

#pragma unroll
        for (int kt = 0; kt < 8; ++kt) {
            const unsigned short* Ahi = (kt < 4) ? hlhi : hmhi;
            const unsigned short* Alo = (kt < 4) ? hllo : hmlo;
            const int rowa = (kt < 4) ? r1a : r2a;
            const int rowb = (kt < 4) ? r1b : r2b;
            const int kbase = (kt & 3) * 32 + lg * 8;
            s16x8 a0h = *(const s16x8*)&Ahi[(size_t)rowa * 128 + kbase];
            s16x8 a0l = *(const s16x8*)&Alo[(size_t)rowa * 128 + kbase];
            s16x8 a1h = *(const s16x8*)&Ahi[(size_t)rowb * 128 + kbase];
            s16x8 a1l = *(const s16x8*)&Alo[(size_t)rowb * 128 + kbase];
#pragma unroll
            for (int nt = 0; nt < 8; ++nt) {
                const int boff = ((nt * 8 + kt) * 64 + l) * 8;
                s16x8 bhi = *(const s16x8*)&whi[boff];
                s16x8 blo = *(const s16x8*)&wlo[boff];
                acc0[nt] = __builtin_amdgcn_mfma_f32_16x16x32_bf16(a0l, bhi, acc0[nt], 0, 0, 0);
                acc0[nt] = __builtin_amdgcn_mfma_f32_16x16x32_bf16(a0h, blo, acc0[nt], 0, 0, 0);
                acc0[nt] = __builtin_amdgcn_mfma_f32_16x16x32_bf16(a0h, bhi, acc0[nt], 0, 0, 0);
                acc1[nt] = __builtin_amdgcn_mfma_f32_16x16x32_bf16(a1l, bhi, acc1[nt], 0, 0, 0);
                acc1[nt] = __builtin_amdgcn_mfma_f32_16x16x32_bf16(a1h, blo, acc1[nt], 0, 0, 0);
                acc1[nt] = __builtin_amdgcn_mfma_f32_16x16x32_bf16(a1h, bhi, acc1[nt], 0, 0, 0);
            }
        }
        // g -> LDS  (D: col = lane&15, row = (lane>>4)*4 + reg)
#pragma unroll
        for (int nt = 0; nt < 8; ++nt) {
            const int col = nt * 16 + lr;
            const float bc = bconst[col];
#pragma unroll
            for (int r = 0; r < 4; ++r) {
                const int row0 = w * 32 + lg * 4 + r;
                float x0 = acc0[nt][r] + bc;
                fus[row0][col]      = 1.0f / (1.0f + expf(-fmaxf(x0, 0.0f)));
                float x1 = acc1[nt][r] + bc;
                fus[row0 + 16][col] = 1.0f / (1.0f + expf(-fmaxf(x1, 0.0f)));
            }
        }
    }
    __syncthreads();

    // ---- fuse: fused = g*(f1+b1) + (1-g)*(f2+bm), in-place (2 threads/pair) ----
    {
        const int p  = t >> 1;
        const int cb = (t & 1) * 64;
        int pidx = pb + p; if (pidx >= P) pidx = P - 1;
        const int r1 = pairs[pidx * 2 + 0];
        const int r2 = pairs[pidx * 2 + 1];
#pragma unroll
        for (int jj = 0; jj < 8; ++jj) {
            const int c = cb + jj * 8;
            s16x8 a1h = *(const s16x8*)&hlhi[(size_t)r1 * 128 + c];
            s16x8 a1l = *(const s16x8*)&hllo[(size_t)r1 * 128 + c];
            s16x8 a2h = *(const s16x8*)&hmhi[(size_t)r2 * 128 + c];
            s16x8 a2l = *(const s16x8*)&hmlo[(size_t)r2 * 128 + c];
            float fo[8];
#pragma unroll
            for (int qq = 0; qq < 8; ++qq) {
                float g  = fus[p][c + qq];
                float v1 = bf16tof((unsigned short)a1h[qq]) + bf16tof((unsigned short)a1l[qq])
                         + b_ll[c + qq];
                float v2 = bf16tof((unsigned short)a2h[qq]) + bf16tof((unsigned short)a2l[qq])
                         + 0.5f * (b_mm[c + qq] + b_lm[c + qq]);
                fo[qq] = g * v1 + (1.0f - g) * v2;
            }
            float4 w0 = {fo[0], fo[1], fo[2], fo[3]};
            float4 w1 = {fo[4], fo[5], fo[6], fo[7]};
            *(float4*)&fus[p][c + 0] = w0;
            *(float4*)&fus[p][c + 4] = w1;
        }
    }
    __syncthreads();

    // ---- c1: [128,128]@[128,64] -> relu -> h1 (overlays fus, stride 68) ----
    {
        const int p0 = (t >> 4) * 8;
        const int o0 = (t & 15) * 4;
        float acc[8][4] = {};
#pragma unroll 2
        for (int k0 = 0; k0 < 128; k0 += 4) {
            float4 w0 = *(const float4*)&c1_W[(k0 + 0) * 64 + o0];
            float4 w1 = *(const float4*)&c1_W[(k0 + 1) * 64 + o0];
            float4 w2 = *(const float4*)&c1_W[(k0 + 2) * 64 + o0];
            float4 w3 = *(const float4*)&c1_W[(k0 + 3) * 64 + o0];
#pragma unroll
            for (int i = 0; i < 8; ++i) {
                float4 a = *(const float4*)&fus[p0 + i][k0];
                fma4(acc[i], a, w0, w1, w2, w3);
            }
        }
        __syncthreads();   // all c1 reads of fus done before h1 overlay
#pragma unroll
        for (int i = 0; i < 8; ++i)
#pragma unroll
            for (int n = 0; n < 4; ++n)
                ldsf[(p0 + i) * 68 + o0 + n] = fmaxf(acc[i][n] + c1_b[o0 + n], 0.0f);
    }
    __syncthreads();

    // ---- c2: [128,64]@[64,32] -> relu -> h2 (base 8704 floats, stride 33; disjoint from h1) ----
    float* h2 = ldsf + 8704;
    {
        const int p0 = (t >> 3) * 4;
        const int o0 = (t & 7) * 4;
        float acc[4][4] = {};
#pragma unroll
        for (int k0 = 0; k0 < 64; k0 += 4) {
            float4 w0 = *(const float4*)&c2_W[(k0 + 0) * 32 + o0];
            float4 w1 = *(const float4*)&c2_W[(k0 + 1) * 32 + o0];
            float4 w2 = *(const float4*)&c2_W[(k0 + 2) * 32 + o0];
            float4 w3 = *(const float4*)&c2_W[(k0 + 3) * 32 + o0];
#pragma unroll
            for (int i = 0; i < 4; ++i) {
                float4 a = *(const float4*)&ldsf[(p0 + i) * 68 + k0];
                fma4(acc[i], a, w0, w1, w2, w3);
            }
        }
        // h2 region [8704, 12928) disjoint from h1 [0, 8704): no barrier needed before write
#pragma unroll
        for (int i = 0; i < 4; ++i)
#pragma unroll
            for (int n = 0; n < 4; ++n)
                h2[(p0 + i) * 33 + o0 + n] = fmaxf(acc[i][n] + c2_b[o0 + n], 0.0f);
    }
    __syncthreads();

    // ---- c3: [128,32]@[32,1] ----
    if (t < 128) {
        int pi = pb + t;
        if (pi < P) {
            float s = c3_b[0];
#pragma unroll
            for (int k = 0; k < 32; ++k) s += h2[t * 33 + k] * c3_W[k];
            out[pi] = s;
        }
    }
}

// ---------------------------------------------------------------- launch
extern "C" void kernel_launch(void* const* d_in, const int* in_sizes, int n_in,
                              void* d_out, int out_size, void* d_ws, size_t ws_size,
                              hipStream_t stream) {
    const float* x_lnc  = (const float*)d_in[0];
    const float* x_mi   = (const float*)d_in[1];
    const float* Wl_ll  = (const float*)d_in[2];
    const float* Wr_ll  = (const float*)d_in[3];
    const float* att_ll = (const float*)d_in[4];
    const float* b_ll   = (const float*)d_in[5];
    const float* Wl_mm  = (const float*)d_in[6];
    const float* Wr_mm  = (const float*)d_in[7];
    const float* att_mm = (const float*)d_in[8];
    const float* b_mm   = (const float*)d_in[9];
    const float* Wl_lm  = (const float*)d_in[10];
    const float* Wr_lm  = (const float*)d_in[11];
    const float* att_lm = (const float*)d_in[12];
    const float* b_lm   = (const float*)d_in[13];
    const float* gate_W = (const float*)d_in[14];
    const float* gate_b = (const float*)d_in[15];
    const float* c1_W   = (const float*)d_in[16];
    const float* c1_b   = (const float*)d_in[17];
    const float* c2_W   = (const float*)d_in[18];
    const float* c2_b   = (const float*)d_in[19];
    const float* c3_W   = (const float*)d_in[20];
    const float* c3_b   = (const float*)d_in[21];
    const int* edge_ll  = (const int*)d_in[22];
    const int* edge_mm  = (const int*)d_in[23];
    const int* edge_lm  = (const int*)d_in[24];
    const int* pairs    = (const int*)d_in[25];

    const int N = in_sizes[0] / 256;    // 30000
    const int E = in_sizes[22] / 2;     // 480000
    const int P = in_sizes[25] / 2;     // 100000

    char* ws = (char*)d_ws;
    size_t o = 0;
    auto alloc = [&](size_t bytes) { char* p = ws + o; o += (bytes + 255) & ~(size_t)255; return p; };

    float* xl            = (float*)alloc((size_t)N * 128 * 4);
    float* xr            = (float*)alloc((size_t)N * 128 * 4);
    unsigned short* hlhi = (unsigned short*)alloc((size_t)N * 128 * 2);
    unsigned short* hllo = (unsigned short*)alloc((size_t)N * 128 * 2);
    unsigned short* hmhi = (unsigned short*)alloc((size_t)N * 128 * 2);
    unsigned short* hmlo = (unsigned short*)alloc((size_t)N * 128 * 2);
    int* perm            = (int*)alloc((size_t)E * 4);
    int* counts3         = (int*)alloc((size_t)3 * N * 4);
    int* base3           = (int*)alloc((size_t)3 * N * 4);
    int* cursor3         = (int*)alloc((size_t)3 * N * 4);
    unsigned short* wshi = (unsigned short*)alloc((size_t)7 * 32768 * 2);
    unsigned short* wslo = (unsigned short*)alloc((size_t)7 * 32768 * 2);
    float* bconst        = (float*)alloc(128 * 4);

    // weight plane index: 0 Wl_ll, 1 Wr_ll, 2 Wl_mm, 3 Wr_mm, 4 Wl_lm, 5 Wr_lm, 6 gate
    auto WHI = [&](int i) { return wshi + (size_t)i * 32768; };
    auto WLO = [&](int i) { return wslo + (size_t)i * 32768; };

    const int egrid     = (E + 255) / 256;
    const int gemm_grid = (N + 63) / 64;
    const int node_grid = (N + 7) / 8;

    split_w7<<<dim3(16, 7), 256, 0, stream>>>(Wl_ll, Wr_ll, Wl_mm, Wr_mm, Wl_lm, Wr_lm,
                                              gate_W, wshi, wslo);
    bconst_k<<<1, 128, 0, stream>>>(gate_W, gate_b, b_ll, b_mm, b_lm, bconst);
    zero_int<<<(3 * N + 255) / 256, 256, 0, stream>>>(counts3, 3 * N);
    hist3<<<dim3(egrid, 3), 256, 0, stream>>>(edge_ll, edge_mm, edge_lm, counts3, E, N);
    scan3<<<3, 1024, 0, stream>>>(counts3, base3, cursor3, N);

    // conv 0: ll
    scatter_edges<<<egrid, 256, 0, stream>>>(edge_ll, edge_ll + E, cursor3, perm, E);
    gemm_mfma<2><<<gemm_grid, 256, 0, stream>>>(x_lnc, WHI(0), WLO(0), WHI(1), WLO(1),
                                                xl, xr, N);
    node_gatv2<0><<<node_grid, 256, 0, stream>>>(xl, xr, att_ll, base3, counts3,
                                                 perm, hlhi, hllo, N);
    // conv 1: mm
    scatter_edges<<<egrid, 256, 0, stream>>>(edge_mm, edge_mm + E, cursor3 + N, perm, E);
    gemm_mfma<2><<<gemm_grid, 256, 0, stream>>>(x_mi, WHI(2), WLO(2), WHI(3), WLO(3),
                                                xl, xr, N);
    node_gatv2<1><<<node_grid, 256, 0, stream>>>(xl, xr, att_mm, base3 + N, counts3 + N,
                                                 perm, hmhi, hmlo, N);
    // conv 2: lm (two different A matrices -> paired single GEMMs in one launch)
    scatter_edges<<<egrid, 256, 0, stream>>>(edge_lm, edge_lm + E, cursor3 + 2 * N, perm, E);
    gemm_mfma_pair<<<dim3(gemm_grid, 2), 256, 0, stream>>>(x_lnc, x_mi,
                                                           WHI(4), WLO(4), WHI(5), WLO(5),
                                                           xl, xr, N);
    node_gatv2<2><<<node_grid, 256, 0, stream>>>(xl, xr, att_lm, base3 + 2 * N,
                                                 counts3 + 2 * N, perm, hmhi, hmlo, N);

    mlp_fused<<<(P + 127) / 128, 256, 0, stream>>>(hlhi, hllo, hmhi, hmlo, pairs, P,
                                                   WHI(6), WLO(6), bconst,
                                                   b_ll, b_mm, b_lm,
                                                   c1_W, c1_b, c2_W, c2_b, c3_W, c3_b,
                                                   (float*)d_out);
}

// Round 12
// 690.217 us; speedup vs baseline: 1.1021x; 1.1021x over previous
//
#include <hip/hip_runtime.h>
#include <cmath>

#define NEG_SLOPE 0.2f

typedef __attribute__((ext_vector_type(4))) float f32x4;
typedef __attribute__((ext_vector_type(8))) short s16x8;

__device__ inline unsigned short bf16rn(float x) {
    unsigned int u = __float_as_uint(x);
    u += 0x7fffu + ((u >> 16) & 1u);
    return (unsigned short)(u >> 16);
}
__device__ inline float bf16tof(unsigned short h) {
    return __uint_as_float(((unsigned int)h) << 16);
}

__device__ inline void fma4(float acc[4], const float4 a, const float4 w0,
                            const float4 w1, const float4 w2, const float4 w3) {
    acc[0] += a.x*w0.x + a.y*w1.x + a.z*w2.x + a.w*w3.x;
    acc[1] += a.x*w0.y + a.y*w1.y + a.z*w2.y + a.w*w3.y;
    acc[2] += a.x*w0.z + a.y*w1.z + a.z*w2.z + a.w*w3.z;
    acc[3] += a.x*w0.w + a.y*w1.w + a.z*w2.w + a.w*w3.w;
}

// ---------------------------------------------------------------- weight split (batched, 7 weights)
__global__ __launch_bounds__(256) void split_w7(const float* __restrict__ w0,
                                                const float* __restrict__ w1,
                                                const float* __restrict__ w2,
                                                const float* __restrict__ w3,
                                                const float* __restrict__ w4,
                                                const float* __restrict__ w5,
                                                const float* __restrict__ w6,
                                                unsigned short* __restrict__ whi,
                                                unsigned short* __restrict__ wlo) {
    const int widx = blockIdx.y;
    const float* W = widx == 0 ? w0 : widx == 1 ? w1 : widx == 2 ? w2 :
                     widx == 3 ? w3 : widx == 4 ? w4 : widx == 5 ? w5 : w6;
    int tid = blockIdx.x * 256 + threadIdx.x;      // 0..4095
    int nt = tid >> 9, kt = (tid >> 6) & 7, l = tid & 63;
    int col   = nt * 16 + (l & 15);
    int kbase = kt * 32 + (l >> 4) * 8;
    size_t base = (size_t)widx * 32768 + (size_t)tid * 8;
#pragma unroll
    for (int j = 0; j < 8; ++j) {
        float x = W[(kbase + j) * 128 + col];
        unsigned short hi = bf16rn(x);
        unsigned short lo = bf16rn(x - bf16tof(hi));
        whi[base + j] = hi;
        wlo[base + j] = lo;
    }
}

// bconst[j] = [b_ll | 0.5(b_mm+b_lm)] @ gate_W + gate_b
__global__ __launch_bounds__(128) void bconst_k(const float* __restrict__ W,
                                                const float* __restrict__ gate_b,
                                                const float* __restrict__ b_ll,
                                                const float* __restrict__ b_mm,
                                                const float* __restrict__ b_lm,
                                                float* __restrict__ bconst) {
    int j = threadIdx.x;
    float s = gate_b[j];
    for (int k = 0; k < 128; ++k) s += b_ll[k] * W[k * 128 + j];
    for (int k = 0; k < 128; ++k)
        s += 0.5f * (b_mm[k] + b_lm[k]) * W[(128 + k) * 128 + j];
    bconst[j] = s;
}

// ---------------------------------------------------------------- CSR build (batched)
__global__ __launch_bounds__(256) void zero_int(int* p, int n) {
    int i = blockIdx.x * 256 + threadIdx.x;
    if (i < n) p[i] = 0;
}

__global__ __launch_bounds__(256) void hist3(const int* __restrict__ e0,
                                             const int* __restrict__ e1,
                                             const int* __restrict__ e2,
                                             int* __restrict__ counts3, int E, int N) {
    int c = blockIdx.y;
    const int* et = (c == 0 ? e0 : c == 1 ? e1 : e2) + E;
    int e = blockIdx.x * 256 + threadIdx.x;
    if (e < E) atomicAdd(&counts3[c * N + et[e]], 1);
}

__global__ __launch_bounds__(1024) void scan3(const int* __restrict__ counts3,
                                              int* __restrict__ base3,
                                              int* __restrict__ cursor3, int n) {
    __shared__ int tot[1024];
    const int c = blockIdx.x;
    const int* counts = counts3 + c * n;
    int* base   = base3 + c * n;
    int* cursor = cursor3 + c * n;
    const int t = threadIdx.x;
    const int chunk = (n + 1023) >> 10;
    const int i0 = t * chunk;
    int s = 0;
    for (int i = 0; i < chunk; ++i) {
        int idx = i0 + i;
        if (idx < n) s += counts[idx];
    }
    tot[t] = s;
    __syncthreads();
    for (int d = 1; d < 1024; d <<= 1) {
        int v = (t >= d) ? tot[t - d] : 0;
        __syncthreads();
        tot[t] += v;
        __syncthreads();
    }
    int run = (t == 0) ? 0 : tot[t - 1];
    for (int i = 0; i < chunk; ++i) {
        int idx = i0 + i;
        if (idx < n) {
            base[idx]   = run;
            cursor[idx] = run;
            run += counts[idx];
        }
    }
}

__global__ __launch_bounds__(256) void scatter_edges(const int* __restrict__ esrc,
                                                     const int* __restrict__ etgt,
                                                     int* __restrict__ cursor,
                                                     int* __restrict__ perm, int E) {
    int e = blockIdx.x * 256 + threadIdx.x;
    if (e >= E) return;
    int pos = atomicAdd(&cursor[etgt[e]], 1);
    perm[pos] = esrc[e];
}

// ---------------------------------------------------------------- MFMA projection GEMM
template <int NW>
__global__ __launch_bounds__(256) void gemm_mfma(const float* __restrict__ A,
                                                 const unsigned short* __restrict__ w1hi,
                                                 const unsigned short* __restrict__ w1lo,
                                                 const unsigned short* __restrict__ w2hi,
                                                 const unsigned short* __restrict__ w2lo,
                                                 float* __restrict__ C1,
                                                 float* __restrict__ C2, int M) {
    const int t = threadIdx.x;
    const int w = t >> 6, l = t & 63;
    const int lg = l >> 4, lr = l & 15;
    const int row  = blockIdx.x * 64 + w * 16 + lr;
    const int arow = row < M ? row : M - 1;

    s16x8 ahi[8], alo[8];
#pragma unroll
    for (int kt = 0; kt < 8; ++kt) {
        const float* ap = &A[(size_t)arow * 256 + kt * 32 + lg * 8];
        float4 f0 = *(const float4*)ap;
        float4 f1 = *(const float4*)(ap + 4);
        float xs[8] = {f0.x, f0.y, f0.z, f0.w, f1.x, f1.y, f1.z, f1.w};
        s16x8 h, lo;
#pragma unroll
        for (int j = 0; j < 8; ++j) {
            unsigned short hh = bf16rn(xs[j]);
            h[j]  = (short)hh;
            lo[j] = (short)bf16rn(xs[j] - bf16tof(hh));
        }
        ahi[kt] = h;
        alo[kt] = lo;
    }

    const int orow0 = blockIdx.x * 64 + w * 16 + lg * 4;
#pragma unroll
    for (int ph = 0; ph < NW; ++ph) {
        const unsigned short* whi = ph ? w2hi : w1hi;
        const unsigned short* wlo = ph ? w2lo : w1lo;
        float* __restrict__ C     = ph ? C2 : C1;
        f32x4 acc[8];
#pragma unroll
        for (int nt = 0; nt < 8; ++nt) acc[nt] = (f32x4){0.f, 0.f, 0.f, 0.f};
#pragma unroll
        for (int kt = 0; kt < 8; ++kt) {
#pragma unroll
            for (int nt = 0; nt < 8; ++nt) {
                const int boff = ((nt * 8 + kt) * 64 + l) * 8;
                s16x8 bhi = *(const s16x8*)&whi[boff];
                s16x8 blo = *(const s16x8*)&wlo[boff];
                acc[nt] = __builtin_amdgcn_mfma_f32_16x16x32_bf16(alo[kt], bhi, acc[nt], 0, 0, 0);
                acc[nt] = __builtin_amdgcn_mfma_f32_16x16x32_bf16(ahi[kt], blo, acc[nt], 0, 0, 0);
                acc[nt] = __builtin_amdgcn_mfma_f32_16x16x32_bf16(ahi[kt], bhi, acc[nt], 0, 0, 0);
            }
        }
#pragma unroll
        for (int nt = 0; nt < 8; ++nt) {
#pragma unroll
            for (int r = 0; r < 4; ++r) {
                int orow = orow0 + r;
                if (orow < M) C[(size_t)orow * 128 + nt * 16 + lr] = acc[nt][r];
            }
        }
    }
}

// two independent single-output GEMMs in one launch (blockIdx.y selects)
__global__ __launch_bounds__(256) void gemm_mfma_pair(const float* __restrict__ A0,
                                                      const float* __restrict__ A1,
                                                      const unsigned short* __restrict__ wahi,
                                                      const unsigned short* __restrict__ walo,
                                                      const unsigned short* __restrict__ wbhi,
                                                      const unsigned short* __restrict__ wblo,
                                                      float* __restrict__ C0,
                                                      float* __restrict__ C1, int M) {
    const int t = threadIdx.x;
    const int w = t >> 6, l = t & 63;
    const int lg = l >> 4, lr = l & 15;
    const int row  = blockIdx.x * 64 + w * 16 + lr;
    const int arow = row < M ? row : M - 1;
    const float* __restrict__ A = blockIdx.y ? A1 : A0;
    const unsigned short* __restrict__ whi = blockIdx.y ? wbhi : wahi;
    const unsigned short* __restrict__ wlo = blockIdx.y ? wblo : walo;
    float* __restrict__ C = blockIdx.y ? C1 : C0;

    s16x8 ahi[8], alo[8];
#pragma unroll
    for (int kt = 0; kt < 8; ++kt) {
        const float* ap = &A[(size_t)arow * 256 + kt * 32 + lg * 8];
        float4 f0 = *(const float4*)ap;
        float4 f1 = *(const float4*)(ap + 4);
        float xs[8] = {f0.x, f0.y, f0.z, f0.w, f1.x, f1.y, f1.z, f1.w};
        s16x8 h, lo;
#pragma unroll
        for (int j = 0; j < 8; ++j) {
            unsigned short hh = bf16rn(xs[j]);
            h[j]  = (short)hh;
            lo[j] = (short)bf16rn(xs[j] - bf16tof(hh));
        }
        ahi[kt] = h;
        alo[kt] = lo;
    }

    f32x4 acc[8];
#pragma unroll
    for (int nt = 0; nt < 8; ++nt) acc[nt] = (f32x4){0.f, 0.f, 0.f, 0.f};
#pragma unroll
    for (int kt = 0; kt < 8; ++kt) {
#pragma unroll
        for (int nt = 0; nt < 8; ++nt) {
            const int boff = ((nt * 8 + kt) * 64 + l) * 8;
            s16x8 bhi = *(const s16x8*)&whi[boff];
            s16x8 blo = *(const s16x8*)&wlo[boff];
            acc[nt] = __builtin_amdgcn_mfma_f32_16x16x32_bf16(alo[kt], bhi, acc[nt], 0, 0, 0);
            acc[nt] = __builtin_amdgcn_mfma_f32_16x16x32_bf16(ahi[kt], blo, acc[nt], 0, 0, 0);
            acc[nt] = __builtin_amdgcn_mfma_f32_16x16x32_bf16(ahi[kt], bhi, acc[nt], 0, 0, 0);
        }
    }
    const int orow0 = blockIdx.x * 64 + w * 16 + lg * 4;
#pragma unroll
    for (int nt = 0; nt < 8; ++nt) {
#pragma unroll
        for (int r = 0; r < 4; ++r) {
            int orow = orow0 + r;
            if (orow < M) C[(size_t)orow * 128 + nt * 16 + lr] = acc[nt][r];
        }
    }
}

// ---------------------------------------------------------------- fused per-node GATv2
// Half-wave (32 lanes) per node; lane q covers channels 4q..4q+3; head = q>>4.
#define LEAKY(z) ((z) > 0.f ? (z) : NEG_SLOPE * (z))
#define HREDUCE(p) { p += __shfl_xor(p, 1); p += __shfl_xor(p, 2); \
                     p += __shfl_xor(p, 4); p += __shfl_xor(p, 8); }

__device__ inline float dot4l(const float4 x, const float4 xr, const float4 a) {
    return LEAKY(x.x + xr.x) * a.x + LEAKY(x.y + xr.y) * a.y +
           LEAKY(x.z + xr.z) * a.z + LEAKY(x.w + xr.w) * a.w;
}

template <int MODE>
__global__ __launch_bounds__(256) void node_gatv2(const float* __restrict__ xl,
                                                  const float* __restrict__ xr,
                                                  const float* __restrict__ att,
                                                  const int* __restrict__ base,
                                                  const int* __restrict__ counts,
                                                  const int* __restrict__ perm,
                                                  unsigned short* __restrict__ hhi,
                                                  unsigned short* __restrict__ hlo,
                                                  int N) {
    const int node = blockIdx.x * 8 + (threadIdx.x >> 5);
    if (node >= N) return;
    const int q = threadIdx.x & 31;

    const float4 xrv  = *(const float4*)&xr[(size_t)node * 128 + q * 4];
    const float4 attv = *(const float4*)&att[q * 4];
    const int b   = base[node];
    const int deg = counts[node];

    float  m   = -INFINITY;
    float  den = 0.0f;
    float4 acc = {0.0f, 0.0f, 0.0f, 0.0f};

    int k = 0;
    for (; k + 3 < deg; k += 4) {
        int s0 = perm[b + k + 0];
        int s1 = perm[b + k + 1];
        int s2 = perm[b + k + 2];
        int s3 = perm[b + k + 3];
        float4 x0 = *(const float4*)&xl[(size_t)s0 * 128 + q * 4];
        float4 x1 = *(const float4*)&xl[(size_t)s1 * 128 + q * 4];
        float4 x2 = *(const float4*)&xl[(size_t)s2 * 128 + q * 4];
        float4 x3 = *(const float4*)&xl[(size_t)s3 * 128 + q * 4];

        float p0 = dot4l(x0, xrv, attv);
        float p1 = dot4l(x1, xrv, attv);
        float p2 = dot4l(x2, xrv, attv);
        float p3 = dot4l(x3, xrv, attv);
        HREDUCE(p0) HREDUCE(p1) HREDUCE(p2) HREDUCE(p3)

        float mn = fmaxf(fmaxf(fmaxf(m, p0), fmaxf(p1, p2)), p3);
        float f  = expf(m  - mn);
        float e0 = expf(p0 - mn);
        float e1 = expf(p1 - mn);
        float e2 = expf(p2 - mn);
        float e3 = expf(p3 - mn);
        den   = den   * f + e0 + e1 + e2 + e3;
        acc.x = acc.x * f + e0 * x0.x + e1 * x1.x + e2 * x2.x + e3 * x3.x;
        acc.y = acc.y * f + e0 * x0.y + e1 * x1.y + e2 * x2.y + e3 * x3.y;
        acc.z = acc.z * f + e0 * x0.z + e1 * x1.z + e2 * x2.z + e3 * x3.z;
        acc.w = acc.w * f + e0 * x0.w + e1 * x1.w + e2 * x2.w + e3 * x3.w;
        m = mn;
    }
    for (; k < deg; ++k) {
        int src = perm[b + k];
        float4 x = *(const float4*)&xl[(size_t)src * 128 + q * 4];
        float p = dot4l(x, xrv, attv);
        HREDUCE(p)
        float mn = fmaxf(m, p);
        float f  = expf(m - mn);
        float ex = expf(p - mn);
        den   = den   * f + ex;
        acc.x = acc.x * f + ex * x.x;
        acc.y = acc.y * f + ex * x.y;
        acc.z = acc.z * f + ex * x.z;
        acc.w = acc.w * f + ex * x.w;
        m = mn;
    }

    const float scale = (MODE == 0) ? 1.0f : 0.5f;
    const float r = scale / fmaxf(den, 1e-16f);
    float o[4] = {acc.x * r, acc.y * r, acc.z * r, acc.w * r};

    const size_t idx = (size_t)node * 128 + q * 4;
    if (MODE == 2) {
        ushort4 ph = *(const ushort4*)&hhi[idx];
        ushort4 pl = *(const ushort4*)&hlo[idx];
        o[0] += bf16tof(ph.x) + bf16tof(pl.x);
        o[1] += bf16tof(ph.y) + bf16tof(pl.y);
        o[2] += bf16tof(ph.z) + bf16tof(pl.z);
        o[3] += bf16tof(ph.w) + bf16tof(pl.w);
    }
    ushort4 vh, vl;
    unsigned short h0 = bf16rn(o[0]); vh.x = h0; vl.x = bf16rn(o[0] - bf16tof(h0));
    unsigned short h1 = bf16rn(o[1]); vh.y = h1; vl.y = bf16rn(o[1] - bf16tof(h1));
    unsigned short h2 = bf16rn(o[2]); vh.z = h2; vl.z = bf16rn(o[2] - bf16tof(h2));
    unsigned short h3 = bf16rn(o[3]); vh.w = h3; vl.w = bf16rn(o[3] - bf16tof(h3));
    *(ushort4*)&hhi[idx] = vh;
    *(ushort4*)&hlo[idx] = vl;
}

// ---------------------------------------------------------------- pair MLP (MFMA gate)
// 64 pairs/block, 4 waves x 16 pairs; single 33.8 KB LDS buffer with overlays
// -> 4 blocks/CU for gather-latency hiding.
__global__ __launch_bounds__(256, 4) void mlp_fused(
        const unsigned short* __restrict__ hlhi, const unsigned short* __restrict__ hllo,
        const unsigned short* __restrict__ hmhi, const unsigned short* __restrict__ hmlo,
        const int* __restrict__ pairs, int P,
        const unsigned short* __restrict__ whi, const unsigned short* __restrict__ wlo,
        const float* __restrict__ bconst,
        const float* __restrict__ b_ll, const float* __restrict__ b_mm,
        const float* __restrict__ b_lm,
        const float* __restrict__ c1_W, const float* __restrict__ c1_b,
        const float* __restrict__ c2_W, const float* __restrict__ c2_b,
        const float* __restrict__ c3_W, const float* __restrict__ c3_b,
        float* __restrict__ out) {
    __shared__ float fus[64][132];        // 33792 B; h1 overlays [0,4352) stride 68; h2 at 4480 stride 33
    float* ldsf = &fus[0][0];
    const int t  = threadIdx.x;
    const int pb = blockIdx.x * 64;

    // ---- gate GEMM via MFMA bf16 hi/lo split ----
    {
        const int w = t >> 6, l = t & 63;
        const int lg = l >> 4, lr = l & 15;
        int pidx = pb + w * 16 + lr; if (pidx >= P) pidx = P - 1;
        const int r1 = pairs[pidx * 2 + 0];
        const int r2 = pairs[pidx * 2 + 1];

        f32x4 acc[8];
#pragma unroll
        for (int nt = 0; nt < 8; ++nt) acc[nt] = (f32x4){0.f, 0.f, 0.f, 0.f};

#pragma unroll
        for (int kt = 0; kt < 8; ++kt) {
            const unsigned short* Ahi = (kt < 4) ? hlhi : hmhi;
            const unsigned short* Alo = (kt < 4) ? hllo : hmlo;
            const int arow  = (kt < 4) ? r1 : r2;
            const int kbase = (kt & 3) * 32 + lg * 8;
            s16x8 ahi = *(const s16x8*)&Ahi[(size_t)arow * 128 + kbase];
            s16x8 alo = *(const s16x8*)&Alo[(size_t)arow * 128 + kbase];
#pragma unroll
            for (int nt = 0; nt < 8; ++nt) {
                const int boff = ((nt * 8 + kt) * 64 + l) * 8;
                s16x8 bhi = *(const s16x8*)&whi[boff];
                s16x8 blo = *(const s16x8*)&wlo[boff];
                acc[nt] = __builtin_amdgcn_mfma_f32_16x16x32_bf16(alo, bhi, acc[nt], 0, 0, 0);
                acc[nt] = __builtin_amdgcn_mfma_f32_16x16x32_bf16(ahi, blo, acc[nt], 0, 0, 0);
                acc[nt] = __builtin_amdgcn_mfma_f32_16x16x32_bf16(ahi, bhi, acc[nt], 0, 0, 0);
            }
        }
#pragma unroll
        for (int nt = 0; nt < 8; ++nt) {
            const int col = nt * 16 + lr;
#pragma unroll
            for (int r = 0; r < 4; ++r) {
                const int row = w * 16 + lg * 4 + r;
                float x  = acc[nt][r] + bconst[col];
                float rl = fmaxf(x, 0.0f);
                fus[row][col] = 1.0f / (1.0f + expf(-rl));
            }
        }
    }
    __syncthreads();

    // ---- fuse: fused = g*(f1+b1) + (1-g)*(f2+bm), in-place ----
    {
        const int p  = t >> 2;
        const int cb = (t & 3) * 32;
        int pidx = pb + p; if (pidx >= P) pidx = P - 1;
        const int r1 = pairs[pidx * 2 + 0];
        const int r2 = pairs[pidx * 2 + 1];
#pragma unroll
        for (int jj = 0; jj < 4; ++jj) {
            const int c = cb + jj * 8;
            s16x8 a1h = *(const s16x8*)&hlhi[(size_t)r1 * 128 + c];
            s16x8 a1l = *(const s16x8*)&hllo[(size_t)r1 * 128 + c];
            s16x8 a2h = *(const s16x8*)&hmhi[(size_t)r2 * 128 + c];
            s16x8 a2l = *(const s16x8*)&hmlo[(size_t)r2 * 128 + c];
            float fo[8];
#pragma unroll
            for (int qq = 0; qq < 8; ++qq) {
                float g  = fus[p][c + qq];
                float v1 = bf16tof((unsigned short)a1h[qq]) + bf16tof((unsigned short)a1l[qq])
                         + b_ll[c + qq];
                float v2 = bf16tof((unsigned short)a2h[qq]) + bf16tof((unsigned short)a2l[qq])
                         + 0.5f * (b_mm[c + qq] + b_lm[c + qq]);
                fo[qq] = g * v1 + (1.0f - g) * v2;
            }
            float4 w0 = {fo[0], fo[1], fo[2], fo[3]};
            float4 w1 = {fo[4], fo[5], fo[6], fo[7]};
            *(float4*)&fus[p][c + 0] = w0;
            *(float4*)&fus[p][c + 4] = w1;
        }
    }
    __syncthreads();

    // ---- c1: [64,128]@[128,64] -> relu -> h1 (overlay [0,4352), stride 68) ----
    {
        const int p0 = (t >> 4) * 4;
        const int o0 = (t & 15) * 4;
        float acc[4][4] = {};
#pragma unroll 2
        for (int k0 = 0; k0 < 128; k0 += 4) {
            float4 a0 = *(const float4*)&fus[p0 + 0][k0];
            float4 a1 = *(const float4*)&fus[p0 + 1][k0];
            float4 a2 = *(const float4*)&fus[p0 + 2][k0];
            float4 a3 = *(const float4*)&fus[p0 + 3][k0];
            float4 w0 = *(const float4*)&c1_W[(k0 + 0) * 64 + o0];
            float4 w1 = *(const float4*)&c1_W[(k0 + 1) * 64 + o0];
            float4 w2 = *(const float4*)&c1_W[(k0 + 2) * 64 + o0];
            float4 w3 = *(const float4*)&c1_W[(k0 + 3) * 64 + o0];
            fma4(acc[0], a0, w0, w1, w2, w3);
            fma4(acc[1], a1, w0, w1, w2, w3);
            fma4(acc[2], a2, w0, w1, w2, w3);
            fma4(acc[3], a3, w0, w1, w2, w3);
        }
        __syncthreads();   // all c1 reads of fus done before h1 overlay
#pragma unroll
        for (int i = 0; i < 4; ++i)
#pragma unroll
            for (int n = 0; n < 4; ++n)
                ldsf[(p0 + i) * 68 + o0 + n] = fmaxf(acc[i][n] + c1_b[o0 + n], 0.0f);
    }
    __syncthreads();

    // ---- c2: [64,64]@[64,32] -> relu -> h2 (base 4480, stride 33; disjoint from h1) ----
    float* h2 = ldsf + 4480;
    {
        const int p0 = (t >> 3) * 2;
        const int o0 = (t & 7) * 4;
        float acc[2][4] = {};
#pragma unroll
        for (int k0 = 0; k0 < 64; k0 += 4) {
            float4 a0 = *(const float4*)&ldsf[(p0 + 0) * 68 + k0];
            float4 a1 = *(const float4*)&ldsf[(p0 + 1) * 68 + k0];
            float4 w0 = *(const float4*)&c2_W[(k0 + 0) * 32 + o0];
            float4 w1 = *(const float4*)&c2_W[(k0 + 1) * 32 + o0];
            float4 w2 = *(const float4*)&c2_W[(k0 + 2) * 32 + o0];
            float4 w3 = *(const float4*)&c2_W[(k0 + 3) * 32 + o0];
            fma4(acc[0], a0, w0, w1, w2, w3);
            fma4(acc[1], a1, w0, w1, w2, w3);
        }
        // h2 region [4480, 6592) disjoint from h1 [0, 4352): no barrier before write
#pragma unroll
        for (int i = 0; i < 2; ++i)
#pragma unroll
            for (int n = 0; n < 4; ++n)
                h2[(p0 + i) * 33 + o0 + n] = fmaxf(acc[i][n] + c2_b[o0 + n], 0.0f);
    }
    __syncthreads();

    // ---- c3: [64,32]@[32,1] ----
    if (t < 64) {
        int pi = pb + t;
        if (pi < P) {
            float s = c3_b[0];
#pragma unroll
            for (int k = 0; k < 32; ++k) s += h2[t * 33 + k] * c3_W[k];
            out[pi] = s;
        }
    }
}

// ---------------------------------------------------------------- launch
extern "C" void kernel_launch(void* const* d_in, const int* in_sizes, int n_in,
                              void* d_out, int out_size, void* d_ws, size_t ws_size,
                              hipStream_t stream) {
    const float* x_lnc  = (const float*)d_in[0];
    const float* x_mi   = (const float*)d_in[1];
    const float* Wl_ll  = (const float*)d_in[2];
    const float* Wr_ll  = (const float*)d_in[3];
    const float* att_ll = (const float*)d_in[4];
    const float* b_ll   = (const float*)d_in[5];
    const float* Wl_mm  = (const float*)d_in[6];
    const float* Wr_mm  = (const float*)d_in[7];
    const float* att_mm = (const float*)d_in[8];
    const float* b_mm   = (const float*)d_in[9];
    const float* Wl_lm  = (const float*)d_in[10];
    const float* Wr_lm  = (const float*)d_in[11];
    const float* att_lm = (const float*)d_in[12];
    const float* b_lm   = (const float*)d_in[13];
    const float* gate_W = (const float*)d_in[14];
    const float* gate_b = (const float*)d_in[15];
    const float* c1_W   = (const float*)d_in[16];
    const float* c1_b   = (const float*)d_in[17];
    const float* c2_W   = (const float*)d_in[18];
    const float* c2_b   = (const float*)d_in[19];
    const float* c3_W   = (const float*)d_in[20];
    const float* c3_b   = (const float*)d_in[21];
    const int* edge_ll  = (const int*)d_in[22];
    const int* edge_mm  = (const int*)d_in[23];
    const int* edge_lm  = (const int*)d_in[24];
    const int* pairs    = (const int*)d_in[25];

    const int N = in_sizes[0] / 256;    // 30000
    const int E = in_sizes[22] / 2;     // 480000
    const int P = in_sizes[25] / 2;     // 100000

    char* ws = (char*)d_ws;
    size_t o = 0;
    auto alloc = [&](size_t bytes) { char* p = ws + o; o += (bytes + 255) & ~(size_t)255; return p; };

    float* xl            = (float*)alloc((size_t)N * 128 * 4);
    float* xr            = (float*)alloc((size_t)N * 128 * 4);
    unsigned short* hlhi = (unsigned short*)alloc((size_t)N * 128 * 2);
    unsigned short* hllo = (unsigned short*)alloc((size_t)N * 128 * 2);
    unsigned short* hmhi = (unsigned short*)alloc((size_t)N * 128 * 2);
    unsigned short* hmlo = (unsigned short*)alloc((size_t)N * 128 * 2);
    int* perm            = (int*)alloc((size_t)E * 4);
    int* counts3         = (int*)alloc((size_t)3 * N * 4);
    int* base3           = (int*)alloc((size_t)3 * N * 4);
    int* cursor3         = (int*)alloc((size_t)3 * N * 4);
    unsigned short* wshi = (unsigned short*)alloc((size_t)7 * 32768 * 2);
    unsigned short* wslo = (unsigned short*)alloc((size_t)7 * 32768 * 2);
    float* bconst        = (float*)alloc(128 * 4);

    // weight plane index: 0 Wl_ll, 1 Wr_ll, 2 Wl_mm, 3 Wr_mm, 4 Wl_lm, 5 Wr_lm, 6 gate
    auto WHI = [&](int i) { return wshi + (size_t)i * 32768; };
    auto WLO = [&](int i) { return wslo + (size_t)i * 32768; };

    const int egrid     = (E + 255) / 256;
    const int gemm_grid = (N + 63) / 64;
    const int node_grid = (N + 7) / 8;

    split_w7<<<dim3(16, 7), 256, 0, stream>>>(Wl_ll, Wr_ll, Wl_mm, Wr_mm, Wl_lm, Wr_lm,
                                              gate_W, wshi, wslo);
    bconst_k<<<1, 128, 0, stream>>>(gate_W, gate_b, b_ll, b_mm, b_lm, bconst);
    zero_int<<<(3 * N + 255) / 256, 256, 0, stream>>>(counts3, 3 * N);
    hist3<<<dim3(egrid, 3), 256, 0, stream>>>(edge_ll, edge_mm, edge_lm, counts3, E, N);
    scan3<<<3, 1024, 0, stream>>>(counts3, base3, cursor3, N);

    // conv 0: ll
    scatter_edges<<<egrid, 256, 0, stream>>>(edge_ll, edge_ll + E, cursor3, perm, E);
    gemm_mfma<2><<<gemm_grid, 256, 0, stream>>>(x_lnc, WHI(0), WLO(0), WHI(1), WLO(1),
                                                xl, xr, N);
    node_gatv2<0><<<node_grid, 256, 0, stream>>>(xl, xr, att_ll, base3, counts3,
                                                 perm, hlhi, hllo, N);
    // conv 1: mm
    scatter_edges<<<egrid, 256, 0, stream>>>(edge_mm, edge_mm + E, cursor3 + N, perm, E);
    gemm_mfma<2><<<gemm_grid, 256, 0, stream>>>(x_mi, WHI(2), WLO(2), WHI(3), WLO(3),
                                                xl, xr, N);
    node_gatv2<1><<<node_grid, 256, 0, stream>>>(xl, xr, att_mm, base3 + N, counts3 + N,
                                                 perm, hmhi, hmlo, N);
    // conv 2: lm (two different A matrices -> paired single GEMMs in one launch)
    scatter_edges<<<egrid, 256, 0, stream>>>(edge_lm, edge_lm + E, cursor3 + 2 * N, perm, E);
    gemm_mfma_pair<<<dim3(gemm_grid, 2), 256, 0, stream>>>(x_lnc, x_mi,
                                                           WHI(4), WLO(4), WHI(5), WLO(5),
                                                           xl, xr, N);
    node_gatv2<2><<<node_grid, 256, 0, stream>>>(xl, xr, att_lm, base3 + 2 * N,
                                                 counts3 + 2 * N, perm, hmhi, hmlo, N);

    mlp_fused<<<(P + 63) / 64, 256, 0, stream>>>(hlhi, hllo, hmhi, hmlo, pairs, P,
                                                 WHI(6), WLO(6), bconst,
                                                 b_ll, b_mm, b_lm,
                                                 c1_W, c1_b, c2_W, c2_b, c3_W, c3_b,
                                                 (float*)d_out);
}